// Round 2
// baseline (401.545 us; speedup 1.0000x reference)
//
#include <hip/hip_runtime.h>

// SAR-ADC 4-bit successive-approximation quantizer.
// Element-wise over N = LENGTH*NADC = 12M floats. Memory-bound:
//   read x (48 MB), write q (48 MB) + Q (192 MB)  -> ~46 us at 6.3 TB/s.
//
// v2: 4 elements/thread, all global accesses 16 B/lane (float4), all
// stores nontemporal (streamed output, no reuse -> don't churn L2).
//
// Numerics: reference does float32 ops throughout. (Q+1)*0.5 is exactly
// 0.0 or 1.0, so each bit_sum = fl(W[m]*VREF) + subset of fl(W[k]*VR),
// added in the reference's fixed order. __fmul_rn/__fadd_rn prevent FMA
// contraction -> bit-exact thresholds -> bit-exact sign decisions.
// sign(x - b + 1e-30) == (x >= b ? +1 : -1): nonzero diffs are >= ~1e-9,
// DELTA only rescues diff==0.

typedef float v4f __attribute__((ext_vector_type(4)));

__global__ __launch_bounds__(256)
void sar_adc_kernel(const v4f* __restrict__ x4, const float* __restrict__ W,
                    v4f* __restrict__ q4, v4f* __restrict__ Q4, int n)
{
    int t = blockIdx.x * blockDim.x + threadIdx.x;   // one thread = 4 elements
    int n4 = n >> 2;                                  // n divisible by 4 (12M)
    if (t >= n4) return;

    const float VREF = 0.1125f;   // fl32(1.8/16)
    const float VR   = 0.1125f;

    // Wave-uniform W loads (compiler lifts to s_load).
    float w0 = W[0], w1 = W[1], w2 = W[2], w3 = W[3], w4 = W[4];
    float w5 = W[5], w6 = W[6], w7 = W[7], w8 = W[8], w9 = W[9];

    // fl(W[k]*VR) terms (exactly the reference's contribution when bit set)
    float wv0 = __fmul_rn(w0, VR);
    float wv1 = __fmul_rn(w1, VR);
    float wv2 = __fmul_rn(w2, VR);
    float wv4 = __fmul_rn(w4, VR);
    float wv5 = __fmul_rn(w5, VR);
    float wv7 = __fmul_rn(w7, VR);

    float b3 = __fmul_rn(w9, VREF);            // j=3 threshold (bit-indep)
    float b2base = __fmul_rn(w8, VREF);
    float b1base = __fmul_rn(w6, VREF);
    float b0base = __fmul_rn(w3, VREF);

    v4f xv = __builtin_nontemporal_load(&x4[t]);

    const float bw0 = 0.1125f, bw1 = 0.225f, bw2 = 0.45f, bw3 = 0.9f;

    v4f qv;
    v4f Qv[4];

    #pragma unroll
    for (int j = 0; j < 4; ++j) {
        float xe = xv[j];

        bool s3 = (xe >= b3);

        float b2 = b2base;
        if (s3) b2 = __fadd_rn(b2, wv7);
        bool s2 = (xe >= b2);

        float b1 = b1base;                     // k=2 then k=3 (ref order)
        if (s2) b1 = __fadd_rn(b1, wv5);
        if (s3) b1 = __fadd_rn(b1, wv4);
        bool s1 = (xe >= b1);

        float b0 = b0base;                     // k=1,2,3 in ref order
        if (s1) b0 = __fadd_rn(b0, wv2);
        if (s2) b0 = __fadd_rn(b0, wv1);
        if (s3) b0 = __fadd_rn(b0, wv0);
        bool s0 = (xe >= b0);

        float qe = s0 ? bw0 : 0.0f;
        if (s1) qe = __fadd_rn(qe, bw1);
        if (s2) qe = __fadd_rn(qe, bw2);
        if (s3) qe = __fadd_rn(qe, bw3);
        qv[j] = qe;

        v4f Qe;
        Qe.x = s0 ? 1.0f : -1.0f;
        Qe.y = s1 ? 1.0f : -1.0f;
        Qe.z = s2 ? 1.0f : -1.0f;
        Qe.w = s3 ? 1.0f : -1.0f;
        Qv[j] = Qe;
    }

    __builtin_nontemporal_store(qv, &q4[t]);
    #pragma unroll
    for (int j = 0; j < 4; ++j)
        __builtin_nontemporal_store(Qv[j], &Q4[4 * t + j]);
}

extern "C" void kernel_launch(void* const* d_in, const int* in_sizes, int n_in,
                              void* d_out, int out_size, void* d_ws, size_t ws_size,
                              hipStream_t stream)
{
    const float* x = (const float*)d_in[0];   // [500000, 24] f32, n = 12M (div by 4)
    const float* W = (const float*)d_in[1];   // [10] f32
    int n = in_sizes[0];

    float* q = (float*)d_out;                 // [n] f32
    float* Q = (float*)d_out + n;             // [n, 4] f32

    const int block = 256;
    const int n4 = n >> 2;
    const int grid = (n4 + block - 1) / block;
    sar_adc_kernel<<<grid, block, 0, stream>>>(
        (const v4f*)x, W, (v4f*)q, (v4f*)Q, n);
}

// Round 3
// 270.914 us; speedup vs baseline: 1.4822x; 1.4822x over previous
//
#include <hip/hip_runtime.h>

// SAR-ADC 4-bit successive-approximation quantizer.
// Element-wise over N = LENGTH*NADC = 12M floats. Memory-bound:
//   read x (48 MB), write q (48 MB) + Q (192 MB).
//
// v3: 4 elements/thread with block-tiled mapping e = blk*1024 + j*256 + tid.
// Every access is per-lane contiguous: x load 1 KB/wave-instr, q store
// 1 KB/wave-instr, Q float4 store 4 KB/wave-instr (full-line writes).
// No nontemporal hints (v2's NT + 64B-lane-stride Q stores caused ~2x
// write amplification: WRITE_SIZE 468 MB vs 245 MB ideal).
//
// Numerics: reference does float32 ops throughout. (Q+1)*0.5 is exactly
// 0.0 or 1.0, so each bit_sum = fl(W[m]*VREF) + subset of fl(W[k]*VR),
// added in the reference's fixed order. __fmul_rn/__fadd_rn prevent FMA
// contraction -> bit-exact thresholds -> bit-exact sign decisions.
// sign(x - b + 1e-30) == (x >= b ? +1 : -1): nonzero diffs are >= ~1e-9,
// DELTA only rescues diff==0.

__global__ __launch_bounds__(256)
void sar_adc_kernel(const float* __restrict__ x, const float* __restrict__ W,
                    float* __restrict__ q_out, float4* __restrict__ Q4, int n)
{
    const int tid  = threadIdx.x;
    const int base = blockIdx.x * 1024 + tid;

    const float VREF = 0.1125f;   // fl32(1.8/16)
    const float VR   = 0.1125f;

    // Wave-uniform W loads (compiler lifts to s_load).
    float w0 = W[0], w1 = W[1], w2 = W[2], w3 = W[3], w4 = W[4];
    float w5 = W[5], w6 = W[6], w7 = W[7], w8 = W[8], w9 = W[9];

    // fl(W[k]*VR) terms (exactly the reference's contribution when bit set)
    float wv0 = __fmul_rn(w0, VR);
    float wv1 = __fmul_rn(w1, VR);
    float wv2 = __fmul_rn(w2, VR);
    float wv4 = __fmul_rn(w4, VR);
    float wv5 = __fmul_rn(w5, VR);
    float wv7 = __fmul_rn(w7, VR);

    float b3     = __fmul_rn(w9, VREF);        // j=3 threshold (bit-indep)
    float b2base = __fmul_rn(w8, VREF);
    float b1base = __fmul_rn(w6, VREF);
    float b0base = __fmul_rn(w3, VREF);

    // Issue all 4 loads up front (4x MLP per thread).
    float xe[4];
    #pragma unroll
    for (int j = 0; j < 4; ++j) {
        int e = base + j * 256;
        if (e < n) xe[j] = x[e];
    }

    const float bw0 = 0.1125f, bw1 = 0.225f, bw2 = 0.45f, bw3 = 0.9f;

    #pragma unroll
    for (int j = 0; j < 4; ++j) {
        int e = base + j * 256;
        if (e >= n) continue;
        float xv = xe[j];

        bool s3 = (xv >= b3);

        float b2 = b2base;
        if (s3) b2 = __fadd_rn(b2, wv7);
        bool s2 = (xv >= b2);

        float b1 = b1base;                     // k=2 then k=3 (ref order)
        if (s2) b1 = __fadd_rn(b1, wv5);
        if (s3) b1 = __fadd_rn(b1, wv4);
        bool s1 = (xv >= b1);

        float b0 = b0base;                     // k=1,2,3 in ref order
        if (s1) b0 = __fadd_rn(b0, wv2);
        if (s2) b0 = __fadd_rn(b0, wv1);
        if (s3) b0 = __fadd_rn(b0, wv0);
        bool s0 = (xv >= b0);

        float qv = s0 ? bw0 : 0.0f;
        if (s1) qv = __fadd_rn(qv, bw1);
        if (s2) qv = __fadd_rn(qv, bw2);
        if (s3) qv = __fadd_rn(qv, bw3);
        q_out[e] = qv;

        float4 Qv;
        Qv.x = s0 ? 1.0f : -1.0f;
        Qv.y = s1 ? 1.0f : -1.0f;
        Qv.z = s2 ? 1.0f : -1.0f;
        Qv.w = s3 ? 1.0f : -1.0f;
        Q4[e] = Qv;                            // 16 B/lane, lane-contiguous
    }
}

extern "C" void kernel_launch(void* const* d_in, const int* in_sizes, int n_in,
                              void* d_out, int out_size, void* d_ws, size_t ws_size,
                              hipStream_t stream)
{
    const float* x = (const float*)d_in[0];   // [500000, 24] f32
    const float* W = (const float*)d_in[1];   // [10] f32
    int n = in_sizes[0];                      // 12,000,000

    float* q  = (float*)d_out;                // [n] f32
    float4* Q = (float4*)((float*)d_out + n); // [n, 4] f32

    const int block = 256;
    const int per_block = 1024;               // 4 elements/thread
    const int grid = (n + per_block - 1) / per_block;
    sar_adc_kernel<<<grid, block, 0, stream>>>(x, W, q, Q, n);
}